// Round 12
// baseline (270.701 us; speedup 1.0000x reference)
//
#include <hip/hip_runtime.h>

#define B_TOT 8192
#define NN 64
#define FF 32
#define ITERS 48
#define THRESH 0.35f

// ws layout:
//   [0..3]                int Tmax (atomicMax target; memset to 0 each launch)
//   [16 .. 16+B*48)       unsigned char selections per batch (ends 393232)
//   [458752 .. +32KB)     int tstop[B] = per-batch firstBelow (split path)
//   [491520 .. +32KB)     float inv[B] = per-batch -1/mean distance
//   [524288 .. +2MB)      float attn[B][64]          (split path only)
//   [4194304 .. +134MB)   float T[B][64][64]: T[b][c][r] = d_b(r,c)  (raw
//                         distances, col-major; s = exp(d*inv) recomputed)
#define TSTOP_OFF (458752)
#define INV_OFF   (491520)
#define ATTN_OFF  (524288)
#define SIMS_OFF  (4194304)
#define WS_NEEDED (SIMS_OFF + (size_t)B_TOT * NN * NN * 4)

// ---------------------------------------------------------------------------
// PROVEN MONOLITHIC KERNEL (fallback for small ws; byte-identical to the r3
// passing build). Do NOT restructure fp-bearing code here.
// ---------------------------------------------------------------------------
__global__ __launch_bounds__(64) void gat_greedy_kernel(
    const float* __restrict__ mail,
    const float* __restrict__ attn_w,
    const float* __restrict__ src_norm,
    int* __restrict__ tmax_ws,
    unsigned char* __restrict__ sels_ws)
{
    const int b = blockIdx.x;
    const int lane = threadIdx.x;

    __shared__ __align__(16) float sims[NN * 65];
    __shared__ __align__(16) float c_lds[NN];
    __shared__ float qarr[NN];
    __shared__ float sarr[NN];

    const float* __restrict__ myrow = mail + ((size_t)b * NN + lane) * FF;
    float a[FF];
#pragma unroll
    for (int k = 0; k < 8; ++k) {
        const float4 v = reinterpret_cast<const float4*>(myrow)[k];
        a[4*k+0] = v.x; a[4*k+1] = v.y; a[4*k+2] = v.z; a[4*k+3] = v.w;
    }
    const float sn = src_norm[b * NN + lane];

    float q0 = 0.f, q1 = 0.f, q2 = 0.f, q3 = 0.f;
#pragma unroll
    for (int k = 0; k < 8; ++k) {
        q0 = fmaf(a[4*k+0], a[4*k+0], q0);
        q1 = fmaf(a[4*k+1], a[4*k+1], q1);
        q2 = fmaf(a[4*k+2], a[4*k+2], q2);
        q3 = fmaf(a[4*k+3], a[4*k+3], q3);
    }
    const float q = (q0 + q1) + (q2 + q3);

    float lg = 0.f;
#pragma unroll
    for (int f = 0; f < FF; ++f) lg = fmaf(a[f], attn_w[f], lg);
    lg *= sn;

    qarr[lane] = q;
    sarr[lane] = sn;
    __syncthreads();

    float mx = lg;
#pragma unroll
    for (int off = 32; off > 0; off >>= 1)
        mx = fmaxf(mx, __shfl_xor(mx, off, 64));
    const float ex = __expf(lg - mx);
    float se = ex;
#pragma unroll
    for (int off = 32; off > 0; off >>= 1)
        se += __shfl_xor(se, off, 64);
    const float attn = ex / se;

    const float sqn = sn * sn * q;
    float dsum = 0.f;
    for (int m = 0; m < NN; ++m) {
        const float4* __restrict__ Am =
            reinterpret_cast<const float4*>(mail + ((size_t)b * NN + m) * FF);
        float g0 = 0.f, g1 = 0.f, g2 = 0.f, g3 = 0.f;
#pragma unroll
        for (int k = 0; k < 8; ++k) {
            const float4 v = Am[k];
            g0 = fmaf(a[4*k+0], v.x, g0);
            g1 = fmaf(a[4*k+1], v.y, g1);
            g2 = fmaf(a[4*k+2], v.z, g2);
            g3 = fmaf(a[4*k+3], v.w, g3);
        }
        const float g  = (g0 + g1) + (g2 + g3);
        const float sm = sarr[m];
        const float qm = qarr[m];
        const float sqm = sm * sm * qm;
        const float d2  = (sqn - 2.f * (sn * sm) * g) + sqm;
        const float d   = sqrtf(fmaxf(d2, 0.f));
        dsum += d;
        sims[lane * 65 + m] = d;
    }

    float tot = dsum;
#pragma unroll
    for (int off = 32; off > 0; off >>= 1)
        tot += __shfl_xor(tot, off, 64);
    const float meand = tot * (1.f / (float)(NN * NN));
    const float inv   = -1.f / meand;   // SIGMA = 1

    float srow[NN];
#pragma unroll
    for (int m = 0; m < NN; ++m) {
        const float d = sims[lane * 65 + m];
        const float s = __expf(d * inv);
        srow[m] = s;
        sims[lane * 65 + m] = s;
    }
#pragma unroll
    for (int m = 0; m < NN; ++m)
        asm volatile("" : "+v"(srow[m]));

    c_lds[lane] = 0.f;
    float c_reg = 0.f;
    __syncthreads();

    int firstBelow = ITERS;
    bool seenBelow = false;

    for (int t = 0; t < ITERS; ++t) {
        float gain = 0.f;
#pragma unroll
        for (int k = 0; k < 16; ++k) {
            const float4 cv = reinterpret_cast<const float4*>(c_lds)[k];
            gain += fmaxf(srow[4*k+0] - cv.x, 0.f);
            gain += fmaxf(srow[4*k+1] - cv.y, 0.f);
            gain += fmaxf(srow[4*k+2] - cv.z, 0.f);
            gain += fmaxf(srow[4*k+3] - cv.w, 0.f);
        }
        gain *= attn;

        float gv = gain; int gi = lane;
#pragma unroll
        for (int off = 32; off > 0; off >>= 1) {
            const float ov = __shfl_xor(gv, off, 64);
            const int   oi = __shfl_xor(gi, off, 64);
            if (ov > gv || (ov == gv && oi < gi)) { gv = ov; gi = oi; }
        }

        if (!seenBelow && gv < THRESH) { firstBelow = t; seenBelow = true; }
        if (lane == 0) sels_ws[(size_t)b * ITERS + t] = (unsigned char)gi;

        const float srl = sims[gi * 65 + lane];
        c_reg = fmaxf(c_reg, srl);
        c_lds[lane] = c_reg;
        __syncthreads();
    }

    if (lane == 0) atomicMax(tmax_ws, firstBelow);
}

// ---------------------------------------------------------------------------
// FUSED PASS A, LDS-light (r12): the 17 KB sims LDS array is deleted. The
// rolled distance loop stashes d to global T instead of LDS (Tb[m*64+lane],
// coalesced 256 B/wave fire-and-forget -- same one store per iteration); the
// exp pass reads it back coalesced (same lane's own store, L2-hot) into
// registers; the ~2 greedy column reads recompute s = __expf(d*inv) from a
// gather (d round-trips exactly, inv is wave-uniform, exp deterministic ->
// bits identical to the proven LDS path). T doubles as the spill: B
// recomputes s from d + inv_g. Every fp expression is byte-identical to the
// proven build. LDS ~1.3 KB -> occupancy no longer LDS-capped (was 9
// blocks/CU = 20%).
// ---------------------------------------------------------------------------
__global__ __launch_bounds__(64) void gat_fusedA_kernel(
    const float* __restrict__ mail,
    const float* __restrict__ attn_w,
    const float* __restrict__ src_norm,
    int* __restrict__ tmax_ws,
    int* __restrict__ tstop_ws,
    unsigned char* __restrict__ sels_ws,
    float* __restrict__ dmat_g,
    float* __restrict__ attn_g,
    float* __restrict__ inv_g)
{
    const int b = blockIdx.x;
    const int lane = threadIdx.x;

    __shared__ __align__(16) float c_lds[NN];
    __shared__ float qarr[NN];
    __shared__ float sarr[NN];

    const float* __restrict__ myrow = mail + ((size_t)b * NN + lane) * FF;
    float a[FF];
#pragma unroll
    for (int k = 0; k < 8; ++k) {
        const float4 v = reinterpret_cast<const float4*>(myrow)[k];
        a[4*k+0] = v.x; a[4*k+1] = v.y; a[4*k+2] = v.z; a[4*k+3] = v.w;
    }
    const float sn = src_norm[b * NN + lane];

    float q0 = 0.f, q1 = 0.f, q2 = 0.f, q3 = 0.f;
#pragma unroll
    for (int k = 0; k < 8; ++k) {
        q0 = fmaf(a[4*k+0], a[4*k+0], q0);
        q1 = fmaf(a[4*k+1], a[4*k+1], q1);
        q2 = fmaf(a[4*k+2], a[4*k+2], q2);
        q3 = fmaf(a[4*k+3], a[4*k+3], q3);
    }
    const float q = (q0 + q1) + (q2 + q3);

    float lg = 0.f;
#pragma unroll
    for (int f = 0; f < FF; ++f) lg = fmaf(a[f], attn_w[f], lg);
    lg *= sn;

    qarr[lane] = q;
    sarr[lane] = sn;
    __syncthreads();

    float mx = lg;
#pragma unroll
    for (int off = 32; off > 0; off >>= 1)
        mx = fmaxf(mx, __shfl_xor(mx, off, 64));
    const float ex = __expf(lg - mx);
    float se = ex;
#pragma unroll
    for (int off = 32; off > 0; off >>= 1)
        se += __shfl_xor(se, off, 64);
    const float attn = ex / se;

    // early attn spill (final value; drains during the distance loop)
    attn_g[b * NN + lane] = attn;

    float* __restrict__ Tb = dmat_g + (size_t)b * NN * NN;

    const float sqn = sn * sn * q;
    float dsum = 0.f;
    for (int m = 0; m < NN; ++m) {
        const float4* __restrict__ Am =
            reinterpret_cast<const float4*>(mail + ((size_t)b * NN + m) * FF);
        float g0 = 0.f, g1 = 0.f, g2 = 0.f, g3 = 0.f;
#pragma unroll
        for (int k = 0; k < 8; ++k) {
            const float4 v = Am[k];
            g0 = fmaf(a[4*k+0], v.x, g0);
            g1 = fmaf(a[4*k+1], v.y, g1);
            g2 = fmaf(a[4*k+2], v.z, g2);
            g3 = fmaf(a[4*k+3], v.w, g3);
        }
        const float g  = (g0 + g1) + (g2 + g3);
        const float sm = sarr[m];
        const float qm = qarr[m];
        const float sqm = sm * sm * qm;
        const float d2  = (sqn - 2.f * (sn * sm) * g) + sqm;
        const float d   = sqrtf(fmaxf(d2, 0.f));
        dsum += d;
        Tb[m * NN + lane] = d;    // was sims[lane*65+m]: coalesced d-stash
    }

    float tot = dsum;
#pragma unroll
    for (int off = 32; off > 0; off >>= 1)
        tot += __shfl_xor(tot, off, 64);
    const float meand = tot * (1.f / (float)(NN * NN));
    const float inv   = -1.f / meand;   // SIGMA = 1

    if (lane == 0) inv_g[b] = inv;

    // exp pass: read own d back (coalesced, L2-hot), s stays in registers
    float srow[NN];
#pragma unroll
    for (int m = 0; m < NN; ++m) {
        const float d = Tb[m * NN + lane];
        const float s = __expf(d * inv);
        srow[m] = s;
    }
#pragma unroll
    for (int m = 0; m < NN; ++m)
        asm volatile("" : "+v"(srow[m]));

    c_lds[lane] = 0.f;
    float c_reg = 0.f;
    __syncthreads();   // also drains the d-stores (vmcnt 0 before barrier)

    int firstBelow = ITERS;

    for (int t = 0; t < ITERS; ++t) {
        float gain = 0.f;
#pragma unroll
        for (int k = 0; k < 16; ++k) {
            const float4 cv = reinterpret_cast<const float4*>(c_lds)[k];
            gain += fmaxf(srow[4*k+0] - cv.x, 0.f);
            gain += fmaxf(srow[4*k+1] - cv.y, 0.f);
            gain += fmaxf(srow[4*k+2] - cv.z, 0.f);
            gain += fmaxf(srow[4*k+3] - cv.w, 0.f);
        }
        gain *= attn;

        float gv = gain; int gi = lane;
#pragma unroll
        for (int off = 32; off > 0; off >>= 1) {
            const float ov = __shfl_xor(gv, off, 64);
            const int   oi = __shfl_xor(gi, off, 64);
            if (ov > gv || (ov == gv && oi < gi)) { gv = ov; gi = oi; }
        }

        if (lane == 0) sels_ws[(size_t)b * ITERS + t] = (unsigned char)gi;

        // s(gi,lane) = exp(d(gi,lane)*inv); d(gi,lane) = Tb[lane*NN+gi]
        const float srl = __expf(Tb[lane * NN + gi] * inv);
        c_reg = fmaxf(c_reg, srl);
        c_lds[lane] = c_reg;
        __syncthreads();

        if (gv < THRESH) { firstBelow = t; break; }   // wave-uniform
    }

    if (lane == 0) {
        atomicMax(tmax_ws, firstBelow);
        tstop_ws[b] = firstBelow;
    }
}

// ---------------------------------------------------------------------------
// PASS B + ACCUM (r10 structure -- 512 B-class LDS so the accum tail runs at
// full occupancy; the r11 17 KB staging regression is reverted). s values are
// recomputed as __expf(d*inv) from the T d-buffer: srow via coalesced loads,
// replay/resume columns via gathers (d round-trip exact, inv exact, exp
// deterministic -> bits identical to the proven path). Accum is the exact r0
// chain; resumed selections stay in sel_lds.
// ---------------------------------------------------------------------------
__global__ __launch_bounds__(64) void gat_greedyB_acc_kernel(
    const float* __restrict__ dmat_g,
    const float* __restrict__ attn_g,
    const float* __restrict__ inv_g,
    const float* __restrict__ mail,
    const float* __restrict__ src_norm,
    const float* __restrict__ dst_norm,
    const int* __restrict__ tmax_ws,
    const int* __restrict__ tstop_ws,
    const unsigned char* __restrict__ sels_ws,
    float* __restrict__ out)
{
    const int b = blockIdx.x;
    const int lane = threadIdx.x;

    const int fb   = tstop_ws[b];
    const int Tmax = *tmax_ws;
    const int tEnd = min(ITERS - 1, Tmax);   // last t whose selection is consumed

    __shared__ __align__(16) float c_lds[NN];
    __shared__ int sel_lds[ITERS];

    const unsigned char* __restrict__ sb = sels_ws + (size_t)b * ITERS;

    if (fb < tEnd) {   // block-uniform condition (barriers below are uniform)
        const float* __restrict__ Tb = dmat_g + (size_t)b * NN * NN;
        const float inv = inv_g[b];

        // srow[c] = s(lane,c) = exp(d(lane,c)*inv); d(lane,c)=Tb[c*NN+lane]
        float srow[NN];
#pragma unroll
        for (int c = 0; c < NN; ++c)
            srow[c] = __expf(Tb[c * NN + lane] * inv);
#pragma unroll
        for (int m = 0; m < NN; ++m)
            asm volatile("" : "+v"(srow[m]));

        const float attn = attn_g[b * NN + lane];

        // replay selections 0..fb to reconstruct c (fmax: exact)
        float c_reg = 0.f;
        for (int j = 0; j <= fb; ++j) {
            const int sel = sb[j];
            c_reg = fmaxf(c_reg, __expf(Tb[lane * NN + sel] * inv));
        }
        c_lds[lane] = c_reg;
        __syncthreads();

        for (int t = fb + 1; t <= tEnd; ++t) {
            float gain = 0.f;
#pragma unroll
            for (int k = 0; k < 16; ++k) {
                const float4 cv = reinterpret_cast<const float4*>(c_lds)[k];
                gain += fmaxf(srow[4*k+0] - cv.x, 0.f);
                gain += fmaxf(srow[4*k+1] - cv.y, 0.f);
                gain += fmaxf(srow[4*k+2] - cv.z, 0.f);
                gain += fmaxf(srow[4*k+3] - cv.w, 0.f);
            }
            gain *= attn;

            float gv = gain; int gi = lane;
#pragma unroll
            for (int off = 32; off > 0; off >>= 1) {
                const float ov = __shfl_xor(gv, off, 64);
                const int   oi = __shfl_xor(gi, off, 64);
                if (ov > gv || (ov == gv && oi < gi)) { gv = ov; gi = oi; }
            }

            if (lane == 0) sel_lds[t] = gi;

            const float srl = __expf(Tb[lane * NN + gi] * inv);
            c_reg = fmaxf(c_reg, srl);
            c_lds[lane] = c_reg;
            __syncthreads();   // also publishes sel_lds[t] for the accum below
        }
    }

    // ---- accum (exact r0 chain), all batches, lanes 0..31 ----
    if (lane < FF) {
        const int C = min(ITERS, Tmax + 1);
        float acc = 0.f;
        for (int t = 0; t < C; ++t) {
            const int sel = (t <= fb) ? (int)sb[t] : sel_lds[t];
            acc = fmaf(mail[((size_t)b * NN + sel) * FF + lane],
                       src_norm[b * NN + sel], acc);
        }
        out[b * FF + lane] = acc * dst_norm[b];
    }
}

// ---------------------------------------------------------------------------
// ACCUM (proven r0 form) -- fallback path only
// ---------------------------------------------------------------------------
__global__ __launch_bounds__(64) void gat_accum_kernel(
    const float* __restrict__ mail,
    const float* __restrict__ src_norm,
    const float* __restrict__ dst_norm,
    const int* __restrict__ tmax_ws,
    const unsigned char* __restrict__ sels_ws,
    float* __restrict__ out)
{
    const int lane = threadIdx.x & 31;
    const int b = blockIdx.x * 2 + (threadIdx.x >> 5);
    const int C = min(ITERS, *tmax_ws + 1);
    const unsigned char* __restrict__ sb = sels_ws + (size_t)b * ITERS;
    float acc = 0.f;
    for (int t = 0; t < C; ++t) {
        const int sel = sb[t];
        acc = fmaf(mail[((size_t)b * NN + sel) * FF + lane],
                   src_norm[b * NN + sel], acc);
    }
    out[b * FF + lane] = acc * dst_norm[b];
}

extern "C" void kernel_launch(void* const* d_in, const int* in_sizes, int n_in,
                              void* d_out, int out_size, void* d_ws, size_t ws_size,
                              hipStream_t stream)
{
    const float* mail     = (const float*)d_in[0];
    const float* attn_w   = (const float*)d_in[1];
    const float* src_norm = (const float*)d_in[2];
    const float* dst_norm = (const float*)d_in[3];
    float* out = (float*)d_out;

    int* tmax_ws = (int*)d_ws;
    unsigned char* sels_ws = (unsigned char*)d_ws + 16;

    hipMemsetAsync(d_ws, 0, 4, stream);   // zero the Tmax word

    if (ws_size >= WS_NEEDED) {
        int*   tstop_ws = (int*)((char*)d_ws + TSTOP_OFF);
        float* inv_g    = (float*)((char*)d_ws + INV_OFF);
        float* attn_g   = (float*)((char*)d_ws + ATTN_OFF);
        float* dmat_g   = (float*)((char*)d_ws + SIMS_OFF);
        gat_fusedA_kernel<<<dim3(B_TOT), dim3(64), 0, stream>>>(
            mail, attn_w, src_norm, tmax_ws, tstop_ws, sels_ws,
            dmat_g, attn_g, inv_g);
        gat_greedyB_acc_kernel<<<dim3(B_TOT), dim3(64), 0, stream>>>(
            dmat_g, attn_g, inv_g, mail, src_norm, dst_norm,
            tmax_ws, tstop_ws, sels_ws, out);
    } else {
        gat_greedy_kernel<<<dim3(B_TOT), dim3(64), 0, stream>>>(
            mail, attn_w, src_norm, tmax_ws, sels_ws);
        gat_accum_kernel<<<dim3(B_TOT / 2), dim3(64), 0, stream>>>(
            mail, src_norm, dst_norm, tmax_ws, sels_ws, out);
    }
}

// Round 13
// 238.506 us; speedup vs baseline: 1.1350x; 1.1350x over previous
//
#include <hip/hip_runtime.h>

#define B_TOT 8192
#define NN 64
#define FF 32
#define ITERS 48
#define THRESH 0.35f

// ws layout:
//   [0..3]                int Tmax (atomicMax target; memset to 0 each launch)
//   [16 .. 16+B*48)       unsigned char selections per batch (ends 393232)
//   [458752 .. +32KB)     int tstop[B] = per-batch firstBelow (split path)
//   [524288 .. +2MB)      float attn[B][64]          (split path only)
//   [4194304 .. +134MB)   float T[B][64][64]: T[b][c][r] = s_b(r,c) col-major
#define TSTOP_OFF (458752)
#define ATTN_OFF  (524288)
#define SIMS_OFF  (4194304)
#define WS_NEEDED (SIMS_OFF + (size_t)B_TOT * NN * NN * 4)

// ---------------------------------------------------------------------------
// PROVEN MONOLITHIC KERNEL (fallback for small ws; byte-identical to the r3
// passing build). Do NOT restructure fp-bearing code here.
// ---------------------------------------------------------------------------
__global__ __launch_bounds__(64) void gat_greedy_kernel(
    const float* __restrict__ mail,
    const float* __restrict__ attn_w,
    const float* __restrict__ src_norm,
    int* __restrict__ tmax_ws,
    unsigned char* __restrict__ sels_ws)
{
    const int b = blockIdx.x;
    const int lane = threadIdx.x;

    __shared__ __align__(16) float sims[NN * 65];
    __shared__ __align__(16) float c_lds[NN];
    __shared__ float qarr[NN];
    __shared__ float sarr[NN];

    const float* __restrict__ myrow = mail + ((size_t)b * NN + lane) * FF;
    float a[FF];
#pragma unroll
    for (int k = 0; k < 8; ++k) {
        const float4 v = reinterpret_cast<const float4*>(myrow)[k];
        a[4*k+0] = v.x; a[4*k+1] = v.y; a[4*k+2] = v.z; a[4*k+3] = v.w;
    }
    const float sn = src_norm[b * NN + lane];

    float q0 = 0.f, q1 = 0.f, q2 = 0.f, q3 = 0.f;
#pragma unroll
    for (int k = 0; k < 8; ++k) {
        q0 = fmaf(a[4*k+0], a[4*k+0], q0);
        q1 = fmaf(a[4*k+1], a[4*k+1], q1);
        q2 = fmaf(a[4*k+2], a[4*k+2], q2);
        q3 = fmaf(a[4*k+3], a[4*k+3], q3);
    }
    const float q = (q0 + q1) + (q2 + q3);

    float lg = 0.f;
#pragma unroll
    for (int f = 0; f < FF; ++f) lg = fmaf(a[f], attn_w[f], lg);
    lg *= sn;

    qarr[lane] = q;
    sarr[lane] = sn;
    __syncthreads();

    float mx = lg;
#pragma unroll
    for (int off = 32; off > 0; off >>= 1)
        mx = fmaxf(mx, __shfl_xor(mx, off, 64));
    const float ex = __expf(lg - mx);
    float se = ex;
#pragma unroll
    for (int off = 32; off > 0; off >>= 1)
        se += __shfl_xor(se, off, 64);
    const float attn = ex / se;

    const float sqn = sn * sn * q;
    float dsum = 0.f;
    for (int m = 0; m < NN; ++m) {
        const float4* __restrict__ Am =
            reinterpret_cast<const float4*>(mail + ((size_t)b * NN + m) * FF);
        float g0 = 0.f, g1 = 0.f, g2 = 0.f, g3 = 0.f;
#pragma unroll
        for (int k = 0; k < 8; ++k) {
            const float4 v = Am[k];
            g0 = fmaf(a[4*k+0], v.x, g0);
            g1 = fmaf(a[4*k+1], v.y, g1);
            g2 = fmaf(a[4*k+2], v.z, g2);
            g3 = fmaf(a[4*k+3], v.w, g3);
        }
        const float g  = (g0 + g1) + (g2 + g3);
        const float sm = sarr[m];
        const float qm = qarr[m];
        const float sqm = sm * sm * qm;
        const float d2  = (sqn - 2.f * (sn * sm) * g) + sqm;
        const float d   = sqrtf(fmaxf(d2, 0.f));
        dsum += d;
        sims[lane * 65 + m] = d;
    }

    float tot = dsum;
#pragma unroll
    for (int off = 32; off > 0; off >>= 1)
        tot += __shfl_xor(tot, off, 64);
    const float meand = tot * (1.f / (float)(NN * NN));
    const float inv   = -1.f / meand;   // SIGMA = 1

    float srow[NN];
#pragma unroll
    for (int m = 0; m < NN; ++m) {
        const float d = sims[lane * 65 + m];
        const float s = __expf(d * inv);
        srow[m] = s;
        sims[lane * 65 + m] = s;
    }
#pragma unroll
    for (int m = 0; m < NN; ++m)
        asm volatile("" : "+v"(srow[m]));

    c_lds[lane] = 0.f;
    float c_reg = 0.f;
    __syncthreads();

    int firstBelow = ITERS;
    bool seenBelow = false;

    for (int t = 0; t < ITERS; ++t) {
        float gain = 0.f;
#pragma unroll
        for (int k = 0; k < 16; ++k) {
            const float4 cv = reinterpret_cast<const float4*>(c_lds)[k];
            gain += fmaxf(srow[4*k+0] - cv.x, 0.f);
            gain += fmaxf(srow[4*k+1] - cv.y, 0.f);
            gain += fmaxf(srow[4*k+2] - cv.z, 0.f);
            gain += fmaxf(srow[4*k+3] - cv.w, 0.f);
        }
        gain *= attn;

        float gv = gain; int gi = lane;
#pragma unroll
        for (int off = 32; off > 0; off >>= 1) {
            const float ov = __shfl_xor(gv, off, 64);
            const int   oi = __shfl_xor(gi, off, 64);
            if (ov > gv || (ov == gv && oi < gi)) { gv = ov; gi = oi; }
        }

        if (!seenBelow && gv < THRESH) { firstBelow = t; seenBelow = true; }
        if (lane == 0) sels_ws[(size_t)b * ITERS + t] = (unsigned char)gi;

        const float srl = sims[gi * 65 + lane];
        c_reg = fmaxf(c_reg, srl);
        c_lds[lane] = c_reg;
        __syncthreads();
    }

    if (lane == 0) atomicMax(tmax_ws, firstBelow);
}

// ---------------------------------------------------------------------------
// FUSED PASS A: byte-identical to the r11 passing build (136 us measured).
// LDS d-stash (cheap exp path; r12 proved the global round-trip costs
// +116 MB HBM fetch), fused coalesced col-major s-spill inside the exp pass,
// wave-uniform break, tstop record.
// ---------------------------------------------------------------------------
__global__ __launch_bounds__(64) void gat_fusedA_kernel(
    const float* __restrict__ mail,
    const float* __restrict__ attn_w,
    const float* __restrict__ src_norm,
    int* __restrict__ tmax_ws,
    int* __restrict__ tstop_ws,
    unsigned char* __restrict__ sels_ws,
    float* __restrict__ sims_g,
    float* __restrict__ attn_g)
{
    const int b = blockIdx.x;
    const int lane = threadIdx.x;

    __shared__ __align__(16) float sims[NN * 65];
    __shared__ __align__(16) float c_lds[NN];
    __shared__ float qarr[NN];
    __shared__ float sarr[NN];

    const float* __restrict__ myrow = mail + ((size_t)b * NN + lane) * FF;
    float a[FF];
#pragma unroll
    for (int k = 0; k < 8; ++k) {
        const float4 v = reinterpret_cast<const float4*>(myrow)[k];
        a[4*k+0] = v.x; a[4*k+1] = v.y; a[4*k+2] = v.z; a[4*k+3] = v.w;
    }
    const float sn = src_norm[b * NN + lane];

    float q0 = 0.f, q1 = 0.f, q2 = 0.f, q3 = 0.f;
#pragma unroll
    for (int k = 0; k < 8; ++k) {
        q0 = fmaf(a[4*k+0], a[4*k+0], q0);
        q1 = fmaf(a[4*k+1], a[4*k+1], q1);
        q2 = fmaf(a[4*k+2], a[4*k+2], q2);
        q3 = fmaf(a[4*k+3], a[4*k+3], q3);
    }
    const float q = (q0 + q1) + (q2 + q3);

    float lg = 0.f;
#pragma unroll
    for (int f = 0; f < FF; ++f) lg = fmaf(a[f], attn_w[f], lg);
    lg *= sn;

    qarr[lane] = q;
    sarr[lane] = sn;
    __syncthreads();

    float mx = lg;
#pragma unroll
    for (int off = 32; off > 0; off >>= 1)
        mx = fmaxf(mx, __shfl_xor(mx, off, 64));
    const float ex = __expf(lg - mx);
    float se = ex;
#pragma unroll
    for (int off = 32; off > 0; off >>= 1)
        se += __shfl_xor(se, off, 64);
    const float attn = ex / se;

    // early attn spill (final value; drains during the distance loop)
    attn_g[b * NN + lane] = attn;

    const float sqn = sn * sn * q;
    float dsum = 0.f;
    for (int m = 0; m < NN; ++m) {
        const float4* __restrict__ Am =
            reinterpret_cast<const float4*>(mail + ((size_t)b * NN + m) * FF);
        float g0 = 0.f, g1 = 0.f, g2 = 0.f, g3 = 0.f;
#pragma unroll
        for (int k = 0; k < 8; ++k) {
            const float4 v = Am[k];
            g0 = fmaf(a[4*k+0], v.x, g0);
            g1 = fmaf(a[4*k+1], v.y, g1);
            g2 = fmaf(a[4*k+2], v.z, g2);
            g3 = fmaf(a[4*k+3], v.w, g3);
        }
        const float g  = (g0 + g1) + (g2 + g3);
        const float sm = sarr[m];
        const float qm = qarr[m];
        const float sqm = sm * sm * qm;
        const float d2  = (sqn - 2.f * (sn * sm) * g) + sqm;
        const float d   = sqrtf(fmaxf(d2, 0.f));
        dsum += d;
        sims[lane * 65 + m] = d;
    }

    float tot = dsum;
#pragma unroll
    for (int off = 32; off > 0; off >>= 1)
        tot += __shfl_xor(tot, off, 64);
    const float meand = tot * (1.f / (float)(NN * NN));
    const float inv   = -1.f / meand;   // SIGMA = 1

    // exp pass with FUSED coalesced spill: T[b][m][lane] = s(lane, m)
    float* __restrict__ Tb = sims_g + (size_t)b * NN * NN;
    float srow[NN];
#pragma unroll
    for (int m = 0; m < NN; ++m) {
        const float d = sims[lane * 65 + m];
        const float s = __expf(d * inv);
        srow[m] = s;
        sims[lane * 65 + m] = s;
        Tb[m * NN + lane] = s;        // contiguous across lanes at each m
    }
#pragma unroll
    for (int m = 0; m < NN; ++m)
        asm volatile("" : "+v"(srow[m]));

    c_lds[lane] = 0.f;
    float c_reg = 0.f;
    __syncthreads();

    int firstBelow = ITERS;

    for (int t = 0; t < ITERS; ++t) {
        float gain = 0.f;
#pragma unroll
        for (int k = 0; k < 16; ++k) {
            const float4 cv = reinterpret_cast<const float4*>(c_lds)[k];
            gain += fmaxf(srow[4*k+0] - cv.x, 0.f);
            gain += fmaxf(srow[4*k+1] - cv.y, 0.f);
            gain += fmaxf(srow[4*k+2] - cv.z, 0.f);
            gain += fmaxf(srow[4*k+3] - cv.w, 0.f);
        }
        gain *= attn;

        float gv = gain; int gi = lane;
#pragma unroll
        for (int off = 32; off > 0; off >>= 1) {
            const float ov = __shfl_xor(gv, off, 64);
            const int   oi = __shfl_xor(gi, off, 64);
            if (ov > gv || (ov == gv && oi < gi)) { gv = ov; gi = oi; }
        }

        if (lane == 0) sels_ws[(size_t)b * ITERS + t] = (unsigned char)gi;

        const float srl = sims[gi * 65 + lane];
        c_reg = fmaxf(c_reg, srl);
        c_lds[lane] = c_reg;
        __syncthreads();

        if (gv < THRESH) { firstBelow = t; break; }   // wave-uniform
    }

    if (lane == 0) {
        atomicMax(tmax_ws, firstBelow);
        tstop_ws[b] = firstBelow;
    }
}

// ---------------------------------------------------------------------------
// RESUME KERNEL (separate from accum so its 17 KB LDS cannot throttle the
// accum tail -- r11's mistake). Non-resumed blocks exit in ~us (their LDS
// footprint is irrelevant). Resumed blocks stage col-major T into the
// r0-proven stride-65 LDS layout (coalesced read; 2-way bank write), replay
// selections 0..fb by exact fmax, then run the proven greedy body for
// t = fb+1..tEnd, writing new selections to GLOBAL sels_ws (r8-proven seam).
// ---------------------------------------------------------------------------
__global__ __launch_bounds__(64) void gat_resumeB_kernel(
    const float* __restrict__ sims_g,
    const float* __restrict__ attn_g,
    const int* __restrict__ tmax_ws,
    const int* __restrict__ tstop_ws,
    unsigned char* __restrict__ sels_ws)
{
    const int b = blockIdx.x;
    const int lane = threadIdx.x;

    const int fb   = tstop_ws[b];
    const int tEnd = min(ITERS - 1, *tmax_ws);   // last t whose selection is consumed
    if (fb >= tEnd) return;                      // pass A already covered 0..tEnd

    __shared__ __align__(16) float sims[NN * 65];
    __shared__ __align__(16) float c_lds[NN];

    const float* __restrict__ Tb = sims_g + (size_t)b * NN * NN;

    // stage T -> LDS stride-65; srow picked up for free (same bits as A's)
    float srow[NN];
#pragma unroll
    for (int c = 0; c < NN; ++c) {
        const float v = Tb[c * NN + lane];   // s(lane, c), coalesced
        sims[lane * 65 + c] = v;
        srow[c] = v;
    }
#pragma unroll
    for (int m = 0; m < NN; ++m)
        asm volatile("" : "+v"(srow[m]));

    const float attn = attn_g[b * NN + lane];

    const unsigned char* __restrict__ sb = sels_ws + (size_t)b * ITERS;

    // replay selections 0..fb to reconstruct c (fmax: exact)
    float c_reg = 0.f;
    __syncthreads();   // staged sims visible to cross-lane reads
    for (int j = 0; j <= fb; ++j) {
        const int sel = sb[j];
        c_reg = fmaxf(c_reg, sims[sel * 65 + lane]);
    }
    c_lds[lane] = c_reg;
    __syncthreads();

    for (int t = fb + 1; t <= tEnd; ++t) {
        float gain = 0.f;
#pragma unroll
        for (int k = 0; k < 16; ++k) {
            const float4 cv = reinterpret_cast<const float4*>(c_lds)[k];
            gain += fmaxf(srow[4*k+0] - cv.x, 0.f);
            gain += fmaxf(srow[4*k+1] - cv.y, 0.f);
            gain += fmaxf(srow[4*k+2] - cv.z, 0.f);
            gain += fmaxf(srow[4*k+3] - cv.w, 0.f);
        }
        gain *= attn;

        float gv = gain; int gi = lane;
#pragma unroll
        for (int off = 32; off > 0; off >>= 1) {
            const float ov = __shfl_xor(gv, off, 64);
            const int   oi = __shfl_xor(gi, off, 64);
            if (ov > gv || (ov == gv && oi < gi)) { gv = ov; gi = oi; }
        }

        if (lane == 0) sels_ws[(size_t)b * ITERS + t] = (unsigned char)gi;

        const float srl = sims[gi * 65 + lane];
        c_reg = fmaxf(c_reg, srl);
        c_lds[lane] = c_reg;
        __syncthreads();
    }
}

// ---------------------------------------------------------------------------
// ACCUM (proven r0 form; 512 B-class LDS -> full occupancy)
// ---------------------------------------------------------------------------
__global__ __launch_bounds__(64) void gat_accum_kernel(
    const float* __restrict__ mail,
    const float* __restrict__ src_norm,
    const float* __restrict__ dst_norm,
    const int* __restrict__ tmax_ws,
    const unsigned char* __restrict__ sels_ws,
    float* __restrict__ out)
{
    const int lane = threadIdx.x & 31;
    const int b = blockIdx.x * 2 + (threadIdx.x >> 5);
    const int C = min(ITERS, *tmax_ws + 1);
    const unsigned char* __restrict__ sb = sels_ws + (size_t)b * ITERS;
    float acc = 0.f;
    for (int t = 0; t < C; ++t) {
        const int sel = sb[t];
        acc = fmaf(mail[((size_t)b * NN + sel) * FF + lane],
                   src_norm[b * NN + sel], acc);
    }
    out[b * FF + lane] = acc * dst_norm[b];
}

extern "C" void kernel_launch(void* const* d_in, const int* in_sizes, int n_in,
                              void* d_out, int out_size, void* d_ws, size_t ws_size,
                              hipStream_t stream)
{
    const float* mail     = (const float*)d_in[0];
    const float* attn_w   = (const float*)d_in[1];
    const float* src_norm = (const float*)d_in[2];
    const float* dst_norm = (const float*)d_in[3];
    float* out = (float*)d_out;

    int* tmax_ws = (int*)d_ws;
    unsigned char* sels_ws = (unsigned char*)d_ws + 16;

    hipMemsetAsync(d_ws, 0, 4, stream);   // zero the Tmax word

    if (ws_size >= WS_NEEDED) {
        int*   tstop_ws = (int*)((char*)d_ws + TSTOP_OFF);
        float* attn_g   = (float*)((char*)d_ws + ATTN_OFF);
        float* sims_g   = (float*)((char*)d_ws + SIMS_OFF);
        gat_fusedA_kernel<<<dim3(B_TOT), dim3(64), 0, stream>>>(
            mail, attn_w, src_norm, tmax_ws, tstop_ws, sels_ws, sims_g, attn_g);
        gat_resumeB_kernel<<<dim3(B_TOT), dim3(64), 0, stream>>>(
            sims_g, attn_g, tmax_ws, tstop_ws, sels_ws);
        gat_accum_kernel<<<dim3(B_TOT / 2), dim3(64), 0, stream>>>(
            mail, src_norm, dst_norm, tmax_ws, sels_ws, out);
    } else {
        gat_greedy_kernel<<<dim3(B_TOT), dim3(64), 0, stream>>>(
            mail, attn_w, src_norm, tmax_ws, sels_ws);
        gat_accum_kernel<<<dim3(B_TOT / 2), dim3(64), 0, stream>>>(
            mail, src_norm, dst_norm, tmax_ws, sels_ws, out);
    }
}